// Round 3
// baseline (785.404 us; speedup 1.0000x reference)
//
#include <hip/hip_runtime.h>
#include <hip/hip_bf16.h>
#include <math.h>

typedef unsigned short ushort_t;
typedef unsigned int u32;

constexpr int D  = 512;
constexpr int T  = 8192;
constexpr int B  = 8;
constexpr int H  = 8;
constexpr int KS = 64;
constexpr int HD = 64;
constexpr float SCALE = 0.125f;
constexpr float LNEPS = 1e-5f;
constexpr float EPS   = 1e-20f;

constexpr int TC  = 128;   // tokens per chunk
constexpr int CPB = 2;     // chunks per block

// ws layout (float units)
constexpr size_t OFF_S    = 0;         // 64*512
constexpr size_t OFF_BQ   = 32768;     // 512
constexpr size_t OFF_SACC = 33280;     // 8*8*64*64 = 262144
constexpr size_t OFF_CACC = 295424;    // 8*8*64 = 4096
constexpr size_t OFF_WB2  = 299520;    // bf16[1024*512] (1 MB) lives here

typedef __attribute__((ext_vector_type(8))) short bf16x8;
typedef __attribute__((ext_vector_type(4))) float f32x4;
typedef __attribute__((ext_vector_type(4))) unsigned short us4;

__device__ __forceinline__ ushort_t f2bf(float x) {
  __hip_bfloat16 t = __float2bfloat16(x);
  return *(ushort_t*)&t;
}

__device__ __forceinline__ u32 pk2bf(float x, float y) {
  __hip_bfloat162 t = __float22bfloat162_rn(make_float2(x, y));
  return *(u32*)&t;
}

__device__ __forceinline__ bf16x8 cvt8(f32x4 a, f32x4 b) {
  union { bf16x8 v; u32 u[4]; } r;
  r.u[0] = pk2bf(a.x, a.y); r.u[1] = pk2bf(a.z, a.w);
  r.u[2] = pk2bf(b.x, b.y); r.u[3] = pk2bf(b.z, b.w);
  return r.v;
}

// ---------- setup: layernorm of slots ----------
__global__ void ln_slots_kernel(const float* __restrict__ slots_w,
                                const float* __restrict__ g, const float* __restrict__ b,
                                float* __restrict__ S) {
  __shared__ float red[8];
  int k = blockIdx.x;
  int tid = threadIdx.x;
  float x0 = slots_w[k*D + tid];
  float x1 = slots_w[k*D + tid + 256];
  float s1 = x0 + x1, s2 = x0*x0 + x1*x1;
  for (int off = 32; off; off >>= 1) { s1 += __shfl_xor(s1, off); s2 += __shfl_xor(s2, off); }
  if ((tid & 63) == 0) { red[tid >> 6] = s1; red[4 + (tid >> 6)] = s2; }
  __syncthreads();
  s1 = red[0] + red[1] + red[2] + red[3];
  s2 = red[4] + red[5] + red[6] + red[7];
  float mu = s1 / D;
  float var = s2 / D - mu * mu;
  float rs = rsqrtf(var + LNEPS);
  S[k*D + tid]       = (x0 - mu) * rs * g[tid]       + b[tid];
  S[k*D + tid + 256] = (x1 - mu) * rs * g[tid + 256] + b[tid + 256];
}

// ---------- setup: Wb2[(h*128+k)][in] = bf16(scale * sum_d S[k][h*64+d] * Wk[h*64+d][in]) ----------
__global__ void weff_kernel(const float* __restrict__ S, const float* __restrict__ Wk,
                            ushort_t* __restrict__ Wb2) {
  int gid = blockIdx.x * 256 + threadIdx.x;   // 0..262143
  int in = gid & 511;
  int hk = gid >> 9;          // uniform per block
  int h = hk >> 6, k = hk & 63;
  const float* srow = S + k*D + h*HD;
  const float* wcol = Wk + (size_t)(h*HD)*D + in;
  float acc = 0.f;
  #pragma unroll 8
  for (int d = 0; d < HD; ++d) acc += srow[d] * wcol[(size_t)d*D];
  Wb2[(size_t)(h*128 + k)*D + in] = f2bf(acc * SCALE);
}

// ---------- setup: bq[hk] = scale * sum_d S[k][h*64+d] * bk[h*64+d] ----------
__global__ void bq_kernel(const float* __restrict__ S, const float* __restrict__ bk,
                          float* __restrict__ bq) {
  int hk = blockIdx.x * 256 + threadIdx.x;
  int h = hk >> 6, k = hk & 63;
  float acc = 0.f;
  for (int d = 0; d < HD; ++d) acc += S[k*D + h*HD + d] * bk[h*HD + d];
  bq[hk] = acc * SCALE;
}

// ---------- setup: Wb2[(h*128+64+d)][in] = bf16(Wv[h*64+d][in]) ----------
__global__ void wvcopy_kernel(const float* __restrict__ Wv, ushort_t* __restrict__ Wb2) {
  int gid = blockIdx.x * 256 + threadIdx.x;   // 0..262143
  int in = gid & 511;
  int hd = gid >> 9;
  int h = hd >> 6, d = hd & 63;
  Wb2[(size_t)(h*128 + 64 + d)*D + in] = f2bf(Wv[(size_t)hd*D + in]);
}

__global__ void zero_kernel(float* __restrict__ p, int n) {
  int gid = blockIdx.x * 256 + threadIdx.x;
  if (gid < n) p[gid] = 0.f;
}

// ---------- main fused MFMA kernel ----------
// grid = 2048 blocks, 256 threads (4 waves, 2x2 wave grid).
// Phase 1 is a barrier-free, LDS-free register-streaming GEMM: each wave loads
// its MFMA A fragments (fp32 X rows, per-lane 16B slices, cvt in-register) and
// B fragments (bf16 weight rows) DIRECTLY from global/L2 with an explicit
// 1-step-ahead register double-buffer (two static sets, full unroll).
// L2 serves the reuse (X chunk shared by 8 co-XCD head-blocks; weight panel is
// 128 KB/head, L2-resident). LDS is used only for the phase-2 W/V overlay.
__global__ __launch_bounds__(256, 2) void main_kernel(
    const float* __restrict__ X, const ushort_t* __restrict__ Wb2,
    const float* __restrict__ bq, const float* __restrict__ bv,
    float* __restrict__ Sacc, float* __restrict__ Cacc) {
  __shared__ __align__(16) char smem[34816];
  ushort_t* W_lds = (ushort_t*)smem;                  // [64 slots][136 tokens] bf16
  ushort_t* V_lds = (ushort_t*)(smem + 17408);        // [64 dims ][136 tokens] bf16

  const int tid  = threadIdx.x;
  const int lane = tid & 63, w = tid >> 6;
  const int wm = w & 1, wn = w >> 1;
  const int m16 = lane & 15, q = lane >> 4;

  const int id = blockIdx.x;
  const int h  = (id >> 3) & 7;
  const int cg = (id & 7) | ((id >> 6) << 3);         // 0..255
  const int bh = (cg >> 5) * H + h;                    // batch*H + head

  // B fragment base pointers: col = wn*64 + j*16 + m16, k-slice q*8..q*8+7
  const ushort_t* bp[4];
  #pragma unroll
  for (int j = 0; j < 4; ++j)
    bp[j] = Wb2 + (size_t)(h * 128 + wn * 64 + j * 16 + m16) * D + q * 8;

  f32x4 acc2[4] = {};                                  // phase-2 accum (16 slots x 64 dims per wave)
  float csum[4] = {0.f, 0.f, 0.f, 0.f};

  for (int cc = 0; cc < CPB; ++cc) {
    const float* Xc = X + (size_t)(cg * CPB + cc) * TC * D;
    // A fragment base pointers: row = wm*64 + i*16 + m16, k-slice q*8..q*8+7
    const float* ap[4];
    #pragma unroll
    for (int i = 0; i < 4; ++i)
      ap[i] = Xc + (size_t)(wm * 64 + i * 16 + m16) * D + q * 8;

    f32x4 acc[4][4] = {};                              // phase-1 accum 64x64 per wave

    // two static register sets for 1-step-ahead prefetch
    f32x4 aL0[4], aH0[4], aL1[4], aH1[4];
    bf16x8 bF0[4], bF1[4];

    // prologue: load K-step 0 into set0
    #pragma unroll
    for (int i = 0; i < 4; ++i) {
      aL0[i] = *(const f32x4*)(ap[i]);
      aH0[i] = *(const f32x4*)(ap[i] + 4);
    }
    #pragma unroll
    for (int j = 0; j < 4; ++j) bF0[j] = *(const bf16x8*)(bp[j]);

    #pragma unroll
    for (int tt = 0; tt < 8; ++tt) {
      const int t1 = 2 * tt + 1;                       // compile-time after unroll
      // prefetch odd step t1 into set1
      #pragma unroll
      for (int i = 0; i < 4; ++i) {
        aL1[i] = *(const f32x4*)(ap[i] + t1 * 32);
        aH1[i] = *(const f32x4*)(ap[i] + t1 * 32 + 4);
      }
      #pragma unroll
      for (int j = 0; j < 4; ++j) bF1[j] = *(const bf16x8*)(bp[j] + t1 * 32);

      // compute even step from set0
      {
        bf16x8 af[4];
        #pragma unroll
        for (int i = 0; i < 4; ++i) af[i] = cvt8(aL0[i], aH0[i]);
        #pragma unroll
        for (int i = 0; i < 4; ++i)
          #pragma unroll
          for (int j = 0; j < 4; ++j)
            acc[i][j] = __builtin_amdgcn_mfma_f32_16x16x32_bf16(af[i], bF0[j], acc[i][j], 0, 0, 0);
      }

      if (tt < 7) {
        const int t2 = 2 * tt + 2;
        // prefetch even step t2 into set0
        #pragma unroll
        for (int i = 0; i < 4; ++i) {
          aL0[i] = *(const f32x4*)(ap[i] + t2 * 32);
          aH0[i] = *(const f32x4*)(ap[i] + t2 * 32 + 4);
        }
        #pragma unroll
        for (int j = 0; j < 4; ++j) bF0[j] = *(const bf16x8*)(bp[j] + t2 * 32);
      }

      // compute odd step from set1
      {
        bf16x8 af[4];
        #pragma unroll
        for (int i = 0; i < 4; ++i) af[i] = cvt8(aL1[i], aH1[i]);
        #pragma unroll
        for (int i = 0; i < 4; ++i)
          #pragma unroll
          for (int j = 0; j < 4; ++j)
            acc[i][j] = __builtin_amdgcn_mfma_f32_16x16x32_bf16(af[i], bF1[j], acc[i][j], 0, 0, 0);
      }
    }

    // ---- softmax / V pack into LDS overlay (phase 1 never touched LDS;
    //      previous chunk's phase-2 reads were fenced by the trailing sync) ----
    if (wn == 0) {
      // these waves hold logits: cols (lane&15)+j*16 = slots, rows = tokens
      float bqv[4];
      #pragma unroll
      for (int j = 0; j < 4; ++j) bqv[j] = bq[h * KS + j * 16 + m16];
      #pragma unroll
      for (int i = 0; i < 4; ++i) {
        us4 wp[4];
        #pragma unroll
        for (int r = 0; r < 4; ++r) {
          float v0 = acc[i][0][r] + bqv[0];
          float v1 = acc[i][1][r] + bqv[1];
          float v2 = acc[i][2][r] + bqv[2];
          float v3 = acc[i][3][r] + bqv[3];
          float mx = fmaxf(fmaxf(v0, v1), fmaxf(v2, v3));
          mx = fmaxf(mx, __shfl_xor(mx, 1));
          mx = fmaxf(mx, __shfl_xor(mx, 2));
          mx = fmaxf(mx, __shfl_xor(mx, 4));
          mx = fmaxf(mx, __shfl_xor(mx, 8));
          v0 = __expf(v0 - mx); v1 = __expf(v1 - mx);
          v2 = __expf(v2 - mx); v3 = __expf(v3 - mx);
          float s = v0 + v1 + v2 + v3;
          s += __shfl_xor(s, 1); s += __shfl_xor(s, 2);
          s += __shfl_xor(s, 4); s += __shfl_xor(s, 8);
          float inv = __builtin_amdgcn_rcpf(s);
          v0 *= inv; v1 *= inv; v2 *= inv; v3 *= inv;
          csum[0] += v0; csum[1] += v1; csum[2] += v2; csum[3] += v3;
          wp[0][r] = f2bf(v0); wp[1][r] = f2bf(v1);
          wp[2][r] = f2bf(v2); wp[3][r] = f2bf(v3);
        }
        #pragma unroll
        for (int j = 0; j < 4; ++j)
          *(us4*)(W_lds + (j * 16 + m16) * 136 + wm * 64 + i * 16 + q * 4) = wp[j];
      }
    } else {
      // these waves hold V: cols = head dims
      float bvv[4];
      #pragma unroll
      for (int j = 0; j < 4; ++j) bvv[j] = bv[h * HD + j * 16 + m16];
      #pragma unroll
      for (int i = 0; i < 4; ++i) {
        #pragma unroll
        for (int j = 0; j < 4; ++j) {
          us4 pk;
          pk.x = f2bf(acc[i][j][0] + bvv[j]);
          pk.y = f2bf(acc[i][j][1] + bvv[j]);
          pk.z = f2bf(acc[i][j][2] + bvv[j]);
          pk.w = f2bf(acc[i][j][3] + bvv[j]);
          *(us4*)(V_lds + (j * 16 + m16) * 136 + wm * 64 + i * 16 + q * 4) = pk;
        }
      }
    }
    __syncthreads();

    // phase 2: S_part[slot][d] += sum_tokens W[slot][t] * V[d][t]; each wave: 16 slots x 64 d
    #pragma unroll
    for (int kk = 0; kk < 4; ++kk) {
      bf16x8 a = *(const bf16x8*)(W_lds + (w * 16 + m16) * 136 + kk * 32 + q * 8);
      #pragma unroll
      for (int j = 0; j < 4; ++j) {
        bf16x8 bb = *(const bf16x8*)(V_lds + (j * 16 + m16) * 136 + kk * 32 + q * 8);
        acc2[j] = __builtin_amdgcn_mfma_f32_16x16x32_bf16(a, bb, acc2[j], 0, 0, 0);
      }
    }
    __syncthreads();   // phase-2 reads done before next chunk overwrites W/V
  }

  // flush accumulators (one atomic pass for both chunks)
  float* Sb = Sacc + (size_t)bh * KS * HD;
  #pragma unroll
  for (int j = 0; j < 4; ++j)
    #pragma unroll
    for (int r = 0; r < 4; ++r)
      atomicAdd(Sb + (w * 16 + q * 4 + r) * HD + j * 16 + m16, acc2[j][r]);

  if (wn == 0) {
    #pragma unroll
    for (int j = 0; j < 4; ++j) {
      float c = csum[j];
      c += __shfl_xor(c, 16);
      c += __shfl_xor(c, 32);
      if (q == 0) atomicAdd(Cacc + (size_t)bh * KS + j * 16 + m16, c);
    }
  }
}

// ---------- finalize: divide by (C+eps), layernorm, write out ----------
__global__ void finalize_kernel(const float* __restrict__ Sacc, const float* __restrict__ Cacc,
                                const float* __restrict__ g, const float* __restrict__ bb,
                                float* __restrict__ out) {
  __shared__ float red[8];
  int bk_ = blockIdx.x;           // b*64 + k
  int b = bk_ >> 6, k = bk_ & 63;
  int tid = threadIdx.x;
  float v[2];
  #pragma unroll
  for (int m = 0; m < 2; ++m) {
    int d = tid + m*256;
    int h = d >> 6, dd = d & 63;
    float c = Cacc[((size_t)b*H + h)*KS + k];
    v[m] = Sacc[(((size_t)b*H + h)*KS + k)*HD + dd] / (c + EPS);
  }
  float s1 = v[0] + v[1], s2 = v[0]*v[0] + v[1]*v[1];
  for (int off = 32; off; off >>= 1) { s1 += __shfl_xor(s1, off); s2 += __shfl_xor(s2, off); }
  if ((tid & 63) == 0) { red[tid >> 6] = s1; red[4 + (tid >> 6)] = s2; }
  __syncthreads();
  s1 = red[0] + red[1] + red[2] + red[3];
  s2 = red[4] + red[5] + red[6] + red[7];
  float mu = s1 / D;
  float var = s2 / D - mu * mu;
  float rs = rsqrtf(var + LNEPS);
  #pragma unroll
  for (int m = 0; m < 2; ++m) {
    int d = tid + m*256;
    out[(size_t)bk_*D + d] = (v[m] - mu) * rs * g[d] + bb[d];
  }
}

extern "C" void kernel_launch(void* const* d_in, const int* in_sizes, int n_in,
                              void* d_out, int out_size, void* d_ws, size_t ws_size,
                              hipStream_t stream) {
  const float* X       = (const float*)d_in[0];
  const float* slots_w = (const float*)d_in[1];
  const float* g_slots = (const float*)d_in[2];
  const float* b_slots = (const float*)d_in[3];
  const float* Wk      = (const float*)d_in[4];
  const float* bk      = (const float*)d_in[5];
  const float* Wv      = (const float*)d_in[6];
  const float* bv      = (const float*)d_in[7];
  const float* g_after = (const float*)d_in[8];
  const float* b_after = (const float*)d_in[9];
  float* ws   = (float*)d_ws;
  float* S    = ws + OFF_S;
  float* bq   = ws + OFF_BQ;
  float* Sacc = ws + OFF_SACC;
  float* Cacc = ws + OFF_CACC;
  ushort_t* Wb2 = (ushort_t*)(ws + OFF_WB2);
  float* out  = (float*)d_out;

  hipLaunchKernelGGL(ln_slots_kernel, dim3(64), dim3(256), 0, stream, slots_w, g_slots, b_slots, S);
  hipLaunchKernelGGL(weff_kernel, dim3(1024), dim3(256), 0, stream, S, Wk, Wb2);
  hipLaunchKernelGGL(bq_kernel, dim3(2), dim3(256), 0, stream, S, bk, bq);
  hipLaunchKernelGGL(wvcopy_kernel, dim3(1024), dim3(256), 0, stream, Wv, Wb2);
  hipLaunchKernelGGL(zero_kernel, dim3(1040), dim3(256), 0, stream, Sacc, 266240);
  hipLaunchKernelGGL(main_kernel, dim3(2048), dim3(256), 0, stream, X, Wb2, bq, bv, Sacc, Cacc);
  hipLaunchKernelGGL(finalize_kernel, dim3(B * KS), dim3(256), 0, stream,
                     Sacc, Cacc, g_after, b_after, out);
}

// Round 6
// 428.992 us; speedup vs baseline: 1.8308x; 1.8308x over previous
//
#include <hip/hip_runtime.h>
#include <hip/hip_bf16.h>
#include <math.h>

typedef unsigned short ushort_t;
typedef unsigned int u32;

constexpr int D  = 512;
constexpr int T  = 8192;
constexpr int B  = 8;
constexpr int H  = 8;
constexpr int KS = 64;
constexpr int HD = 64;
constexpr float SCALE = 0.125f;
constexpr float LNEPS = 1e-5f;
constexpr float EPS   = 1e-20f;

constexpr int TC  = 128;   // tokens per chunk
constexpr int CPB = 2;     // chunks per block

// ws layout (float units)
constexpr size_t OFF_S    = 0;         // 64*512
constexpr size_t OFF_BQ   = 32768;     // 512
constexpr size_t OFF_SACC = 33280;     // 8*8*64*64 = 262144
constexpr size_t OFF_CACC = 295424;    // 8*8*64 = 4096
constexpr size_t OFF_WB2  = 299520;    // bf16[1024*512] (1 MB) lives here

typedef __attribute__((ext_vector_type(8))) short bf16x8;
typedef __attribute__((ext_vector_type(4))) float f32x4;
typedef __attribute__((ext_vector_type(4))) unsigned short us4;

typedef const __attribute__((address_space(1))) u32* gas_ptr;
typedef __attribute__((address_space(3))) u32* las_ptr;

__device__ __forceinline__ void gload16(const void* g, void* l) {
  __builtin_amdgcn_global_load_lds((gas_ptr)g, (las_ptr)l, 16, 0, 0);
}

__device__ __forceinline__ ushort_t f2bf(float x) {
  __hip_bfloat16 t = __float2bfloat16(x);
  return *(ushort_t*)&t;
}

__device__ __forceinline__ u32 pk2bf(float x, float y) {
  __hip_bfloat162 t = __float22bfloat162_rn(make_float2(x, y));
  return *(u32*)&t;
}

__device__ __forceinline__ bf16x8 cvt8(f32x4 a, f32x4 b) {
  union { bf16x8 v; u32 u[4]; } r;
  r.u[0] = pk2bf(a.x, a.y); r.u[1] = pk2bf(a.z, a.w);
  r.u[2] = pk2bf(b.x, b.y); r.u[3] = pk2bf(b.z, b.w);
  return r.v;
}

// ---------- setup: layernorm of slots + fused bq (wave w == head w / 4+w) ----------
__global__ void ln_slots_kernel(const float* __restrict__ slots_w,
                                const float* __restrict__ g, const float* __restrict__ b,
                                const float* __restrict__ bk,
                                float* __restrict__ S, float* __restrict__ bq) {
  __shared__ float red[8];
  int k = blockIdx.x;
  int tid = threadIdx.x;
  float x0 = slots_w[k*D + tid];
  float x1 = slots_w[k*D + tid + 256];
  float s1 = x0 + x1, s2 = x0*x0 + x1*x1;
  for (int off = 32; off; off >>= 1) { s1 += __shfl_xor(s1, off); s2 += __shfl_xor(s2, off); }
  if ((tid & 63) == 0) { red[tid >> 6] = s1; red[4 + (tid >> 6)] = s2; }
  __syncthreads();
  s1 = red[0] + red[1] + red[2] + red[3];
  s2 = red[4] + red[5] + red[6] + red[7];
  float mu = s1 / D;
  float var = s2 / D - mu * mu;
  float rs = rsqrtf(var + LNEPS);
  float y0 = (x0 - mu) * rs * g[tid]       + b[tid];
  float y1 = (x1 - mu) * rs * g[tid + 256] + b[tid + 256];
  S[k*D + tid]       = y0;
  S[k*D + tid + 256] = y1;
  // bq[h][k]: wave w sums d in [64w,64w+64) via y0 (head w) and [256+64w,..) via y1 (head 4+w)
  float p0 = y0 * bk[tid];
  float p1 = y1 * bk[tid + 256];
  for (int off = 32; off; off >>= 1) { p0 += __shfl_xor(p0, off); p1 += __shfl_xor(p1, off); }
  if ((tid & 63) == 0) {
    int w = tid >> 6;
    bq[w * KS + k]       = p0 * SCALE;
    bq[(4 + w) * KS + k] = p1 * SCALE;
  }
}

// ---------- fused setup: weff (id<1024) | wvcopy (1024..2047) | zero (2048..) ----------
__global__ void setup_kernel(const float* __restrict__ S, const float* __restrict__ Wk,
                             const float* __restrict__ Wv,
                             ushort_t* __restrict__ Wb2, float* __restrict__ Sacc) {
  int id = blockIdx.x;
  int tid = threadIdx.x;
  if (id < 1024) {
    int gid = id * 256 + tid;   // 0..262143
    int in = gid & 511;
    int hk = gid >> 9;          // uniform per block
    int h = hk >> 6, k = hk & 63;
    const float* srow = S + k*D + h*HD;
    const float* wcol = Wk + (size_t)(h*HD)*D + in;
    float acc = 0.f;
    #pragma unroll 8
    for (int d = 0; d < HD; ++d) acc += srow[d] * wcol[(size_t)d*D];
    Wb2[(size_t)(h*128 + k)*D + in] = f2bf(acc * SCALE);
  } else if (id < 2048) {
    int gid = (id - 1024) * 256 + tid;
    int in = gid & 511;
    int hd = gid >> 9;
    int h = hd >> 6, d = hd & 63;
    Wb2[(size_t)(h*128 + 64 + d)*D + in] = f2bf(Wv[(size_t)hd*D + in]);
  } else {
    int gid = (id - 2048) * 256 + tid;
    if (gid < 266240) Sacc[gid] = 0.f;
  }
}

// ---------- main fused MFMA kernel ----------
// grid = 2048 blocks, 256 threads (4 waves, 2x2 wave grid).
// ROUND-2 SKELETON (proven): 2 LDS A-buffers, 2 barriers per K-step,
// sched_barrier(0)-sealed stage sections, counted wait = full next-step op
// count (permutation-invariant: "retire everything except the newest step").
// Delta vs round 2: B (bf16 weights) loaded DIRECTLY global->VGPR in the stage
// section (4 reg loads replace 2 B-DMAs; LDS 48->32 KB; B LDS reads gone),
// so per-step issue = 4 A-DMA + 4 B-reg = 8 ops -> s_waitcnt vmcnt(8).
__global__ __launch_bounds__(256, 3) void main_kernel(
    const float* __restrict__ X, const ushort_t* __restrict__ Wb2,
    const float* __restrict__ bq, const float* __restrict__ bv,
    float* __restrict__ Sacc, float* __restrict__ Cacc) {
  __shared__ __align__(16) char smem[34816];
  float*    A0 = (float*)smem;                        // [128][32] fp32, 16 KB
  float*    A1 = (float*)(smem + 16384);              // 16 KB
  ushort_t* W_lds = (ushort_t*)smem;                  // [64 slots][136 tokens] bf16 (overlay)
  ushort_t* V_lds = (ushort_t*)(smem + 17408);        // [64 dims ][136 tokens] bf16 (overlay)

  const int tid  = threadIdx.x;
  const int lane = tid & 63, w = tid >> 6;
  const int wm = w & 1, wn = w >> 1;
  const int m16 = lane & 15, q = lane >> 4;

  const int id = blockIdx.x;
  const int h  = (id >> 3) & 7;
  const int cg = (id & 7) | ((id >> 6) << 3);         // 0..255
  const int bh = (cg >> 5) * H + h;                    // batch*H + head

  // B fragment base pointers: col = wn*64 + j*16 + m16, k-slice q*8..q*8+7
  const ushort_t* bp[4];
  #pragma unroll
  for (int j = 0; j < 4; ++j)
    bp[j] = Wb2 + (size_t)(h * 128 + wn * 64 + j * 16 + m16) * D + q * 8;

  f32x4 acc2[4] = {};                                  // phase-2 accum (16 slots x 64 dims per wave)
  float csum[4] = {0.f, 0.f, 0.f, 0.f};

#define STAGE_A(t, AB) do { \
    _Pragma("unroll") \
    for (int m_ = 0; m_ < 4; ++m_) { \
      int li_ = tid + m_ * 256; \
      int row_ = li_ >> 3, c_ = li_ & 7; \
      gload16(Xc + (size_t)row_ * D + (t) * 32 + ((c_ ^ (row_ & 7)) * 4), \
              (AB) + (size_t)li_ * 4); \
    } \
  } while (0)

#define LOAD_B(t, reg) do { \
    _Pragma("unroll") \
    for (int j_ = 0; j_ < 4; ++j_) reg[j_] = *(const bf16x8*)(bp[j_] + (t) * 32); \
  } while (0)

#define COMPUTE(t, AB, BCUR) do { \
    bf16x8 af_[4]; \
    _Pragma("unroll") \
    for (int i_ = 0; i_ < 4; ++i_) { \
      int r_ = wm * 64 + i_ * 16 + m16; \
      int sw_ = r_ & 7; \
      f32x4 a0_ = *(const f32x4*)((AB) + (size_t)r_ * 32 + (((2 * q)     ^ sw_) * 4)); \
      f32x4 a1_ = *(const f32x4*)((AB) + (size_t)r_ * 32 + (((2 * q + 1) ^ sw_) * 4)); \
      af_[i_] = cvt8(a0_, a1_); \
    } \
    _Pragma("unroll") \
    for (int i_ = 0; i_ < 4; ++i_) \
      _Pragma("unroll") \
      for (int j_ = 0; j_ < 4; ++j_) \
        acc[i_][j_] = __builtin_amdgcn_mfma_f32_16x16x32_bf16(af_[i_], BCUR[j_], acc[i_][j_], 0, 0, 0); \
  } while (0)

// round-2 step: stage(t+1) -> wait(all of step t retired) -> barrier -> compute(t)
// -> barrier (protect buffer t&1 before step t+1 overwrites buffer (t+2)&1 == t&1... 
//    i.e. before ANY wave's next-step stage can touch the buffer we just read)
#define STEP(t, AB, ABN, BCUR, BNXT) do { \
    if ((t) < 15) { \
      STAGE_A((t) + 1, ABN); \
      LOAD_B((t) + 1, BNXT); \
      asm volatile("s_waitcnt vmcnt(8)" ::: "memory"); \
    } else { \
      asm volatile("s_waitcnt vmcnt(0)" ::: "memory"); \
    } \
    __builtin_amdgcn_s_barrier(); \
    __builtin_amdgcn_sched_barrier(0); \
    COMPUTE(t, AB, BCUR); \
    if ((t) < 15) { \
      __builtin_amdgcn_sched_barrier(0); \
      __builtin_amdgcn_s_barrier(); \
    } \
  } while (0)

  for (int cc = 0; cc < CPB; ++cc) {
    const float* Xc = X + (size_t)(cg * CPB + cc) * TC * D;
    f32x4 acc[4][4] = {};                              // phase-1 accum 64x64 per wave
    bf16x8 bF0[4], bF1[4];

    // prologue: stage step 0 (4 A-DMA + 4 B-reg), sealed
    STAGE_A(0, A0);
    LOAD_B(0, bF0);
    __builtin_amdgcn_sched_barrier(0);

    STEP( 0, A0, A1, bF0, bF1);  STEP( 1, A1, A0, bF1, bF0);
    STEP( 2, A0, A1, bF0, bF1);  STEP( 3, A1, A0, bF1, bF0);
    STEP( 4, A0, A1, bF0, bF1);  STEP( 5, A1, A0, bF1, bF0);
    STEP( 6, A0, A1, bF0, bF1);  STEP( 7, A1, A0, bF1, bF0);
    STEP( 8, A0, A1, bF0, bF1);  STEP( 9, A1, A0, bF1, bF0);
    STEP(10, A0, A1, bF0, bF1);  STEP(11, A1, A0, bF1, bF0);
    STEP(12, A0, A1, bF0, bF1);  STEP(13, A1, A0, bF1, bF0);
    STEP(14, A0, A1, bF0, bF1);  STEP(15, A1, A0, bF1, bF0);

    __syncthreads();   // phase-1 LDS reads done; safe to overwrite with W/V overlay

    if (wn == 0) {
      // these waves hold logits: cols (lane&15)+j*16 = slots, rows = tokens
      float bqv[4];
      #pragma unroll
      for (int j = 0; j < 4; ++j) bqv[j] = bq[h * KS + j * 16 + m16];
      #pragma unroll
      for (int i = 0; i < 4; ++i) {
        us4 wp[4];
        #pragma unroll
        for (int r = 0; r < 4; ++r) {
          float v0 = acc[i][0][r] + bqv[0];
          float v1 = acc[i][1][r] + bqv[1];
          float v2 = acc[i][2][r] + bqv[2];
          float v3 = acc[i][3][r] + bqv[3];
          float mx = fmaxf(fmaxf(v0, v1), fmaxf(v2, v3));
          mx = fmaxf(mx, __shfl_xor(mx, 1));
          mx = fmaxf(mx, __shfl_xor(mx, 2));
          mx = fmaxf(mx, __shfl_xor(mx, 4));
          mx = fmaxf(mx, __shfl_xor(mx, 8));
          v0 = __expf(v0 - mx); v1 = __expf(v1 - mx);
          v2 = __expf(v2 - mx); v3 = __expf(v3 - mx);
          float s = v0 + v1 + v2 + v3;
          s += __shfl_xor(s, 1); s += __shfl_xor(s, 2);
          s += __shfl_xor(s, 4); s += __shfl_xor(s, 8);
          float inv = __builtin_amdgcn_rcpf(s);
          v0 *= inv; v1 *= inv; v2 *= inv; v3 *= inv;
          csum[0] += v0; csum[1] += v1; csum[2] += v2; csum[3] += v3;
          wp[0][r] = f2bf(v0); wp[1][r] = f2bf(v1);
          wp[2][r] = f2bf(v2); wp[3][r] = f2bf(v3);
        }
        #pragma unroll
        for (int j = 0; j < 4; ++j)
          *(us4*)(W_lds + (j * 16 + m16) * 136 + wm * 64 + i * 16 + q * 4) = wp[j];
      }
    } else {
      // these waves hold V: cols = head dims
      float bvv[4];
      #pragma unroll
      for (int j = 0; j < 4; ++j) bvv[j] = bv[h * HD + j * 16 + m16];
      #pragma unroll
      for (int i = 0; i < 4; ++i) {
        #pragma unroll
        for (int j = 0; j < 4; ++j) {
          us4 pk;
          pk.x = f2bf(acc[i][j][0] + bvv[j]);
          pk.y = f2bf(acc[i][j][1] + bvv[j]);
          pk.z = f2bf(acc[i][j][2] + bvv[j]);
          pk.w = f2bf(acc[i][j][3] + bvv[j]);
          *(us4*)(V_lds + (j * 16 + m16) * 136 + wm * 64 + i * 16 + q * 4) = pk;
        }
      }
    }
    __syncthreads();

    // phase 2: S_part[slot][d] += sum_tokens W[slot][t] * V[d][t]; each wave: 16 slots x 64 d
    #pragma unroll
    for (int kk = 0; kk < 4; ++kk) {
      bf16x8 a = *(const bf16x8*)(W_lds + (w * 16 + m16) * 136 + kk * 32 + q * 8);
      #pragma unroll
      for (int j = 0; j < 4; ++j) {
        bf16x8 bb = *(const bf16x8*)(V_lds + (j * 16 + m16) * 136 + kk * 32 + q * 8);
        acc2[j] = __builtin_amdgcn_mfma_f32_16x16x32_bf16(a, bb, acc2[j], 0, 0, 0);
      }
    }
    __syncthreads();   // phase-2 reads done before next chunk's staging overwrites overlay
  }

#undef STEP
#undef COMPUTE
#undef LOAD_B
#undef STAGE_A

  // flush accumulators (one atomic pass for both chunks)
  float* Sb = Sacc + (size_t)bh * KS * HD;
  #pragma unroll
  for (int j = 0; j < 4; ++j)
    #pragma unroll
    for (int r = 0; r < 4; ++r)
      atomicAdd(Sb + (w * 16 + q * 4 + r) * HD + j * 16 + m16, acc2[j][r]);

  if (wn == 0) {
    #pragma unroll
    for (int j = 0; j < 4; ++j) {
      float c = csum[j];
      c += __shfl_xor(c, 16);
      c += __shfl_xor(c, 32);
      if (q == 0) atomicAdd(Cacc + (size_t)bh * KS + j * 16 + m16, c);
    }
  }
}

// ---------- finalize: divide by (C+eps), layernorm, write out ----------
__global__ void finalize_kernel(const float* __restrict__ Sacc, const float* __restrict__ Cacc,
                                const float* __restrict__ g, const float* __restrict__ bb,
                                float* __restrict__ out) {
  __shared__ float red[8];
  int bk_ = blockIdx.x;           // b*64 + k
  int b = bk_ >> 6, k = bk_ & 63;
  int tid = threadIdx.x;
  float v[2];
  #pragma unroll
  for (int m = 0; m < 2; ++m) {
    int d = tid + m*256;
    int h = d >> 6, dd = d & 63;
    float c = Cacc[((size_t)b*H + h)*KS + k];
    v[m] = Sacc[(((size_t)b*H + h)*KS + k)*HD + dd] / (c + EPS);
  }
  float s1 = v[0] + v[1], s2 = v[0]*v[0] + v[1]*v[1];
  for (int off = 32; off; off >>= 1) { s1 += __shfl_xor(s1, off); s2 += __shfl_xor(s2, off); }
  if ((tid & 63) == 0) { red[tid >> 6] = s1; red[4 + (tid >> 6)] = s2; }
  __syncthreads();
  s1 = red[0] + red[1] + red[2] + red[3];
  s2 = red[4] + red[5] + red[6] + red[7];
  float mu = s1 / D;
  float var = s2 / D - mu * mu;
  float rs = rsqrtf(var + LNEPS);
  #pragma unroll
  for (int m = 0; m < 2; ++m) {
    int d = tid + m*256;
    out[(size_t)bk_*D + d] = (v[m] - mu) * rs * g[d] + bb[d];
  }
}

extern "C" void kernel_launch(void* const* d_in, const int* in_sizes, int n_in,
                              void* d_out, int out_size, void* d_ws, size_t ws_size,
                              hipStream_t stream) {
  const float* X       = (const float*)d_in[0];
  const float* slots_w = (const float*)d_in[1];
  const float* g_slots = (const float*)d_in[2];
  const float* b_slots = (const float*)d_in[3];
  const float* Wk      = (const float*)d_in[4];
  const float* bk      = (const float*)d_in[5];
  const float* Wv      = (const float*)d_in[6];
  const float* bv      = (const float*)d_in[7];
  const float* g_after = (const float*)d_in[8];
  const float* b_after = (const float*)d_in[9];
  float* ws   = (float*)d_ws;
  float* S    = ws + OFF_S;
  float* bq   = ws + OFF_BQ;
  float* Sacc = ws + OFF_SACC;
  float* Cacc = ws + OFF_CACC;
  ushort_t* Wb2 = (ushort_t*)(ws + OFF_WB2);
  float* out  = (float*)d_out;

  hipLaunchKernelGGL(ln_slots_kernel, dim3(64), dim3(256), 0, stream,
                     slots_w, g_slots, b_slots, bk, S, bq);
  hipLaunchKernelGGL(setup_kernel, dim3(3088), dim3(256), 0, stream, S, Wk, Wv, Wb2, Sacc);
  hipLaunchKernelGGL(main_kernel, dim3(2048), dim3(256), 0, stream, X, Wb2, bq, bv, Sacc, Cacc);
  hipLaunchKernelGGL(finalize_kernel, dim3(B * KS), dim3(256), 0, stream,
                     Sacc, Cacc, g_after, b_after, out);
}

// Round 7
// 417.089 us; speedup vs baseline: 1.8831x; 1.0285x over previous
//
#include <hip/hip_runtime.h>
#include <hip/hip_bf16.h>
#include <math.h>

typedef unsigned short ushort_t;
typedef unsigned int u32;

constexpr int D  = 512;
constexpr int T  = 8192;
constexpr int B  = 8;
constexpr int H  = 8;
constexpr int KS = 64;
constexpr int HD = 64;
constexpr float SCALE = 0.125f;
constexpr float LNEPS = 1e-5f;
constexpr float EPS   = 1e-20f;

constexpr int TC  = 128;   // tokens per chunk
constexpr int CPB = 2;     // chunks per block

// ws layout (float units)
constexpr size_t OFF_S    = 0;         // 64*512
constexpr size_t OFF_BQ   = 32768;     // 512
constexpr size_t OFF_SACC = 33280;     // 8*8*64*64 = 262144
constexpr size_t OFF_CACC = 295424;    // 8*8*64 = 4096
constexpr size_t OFF_WB2  = 299520;    // bf16[1024*512] (1 MB)
constexpr size_t OFF_XB   = 561664;    // bf16[8*8192*512] (64 MB) — optional

typedef __attribute__((ext_vector_type(8))) short bf16x8;
typedef __attribute__((ext_vector_type(4))) float f32x4;
typedef __attribute__((ext_vector_type(4))) unsigned short us4;

typedef const __attribute__((address_space(1))) u32* gas_ptr;
typedef __attribute__((address_space(3))) u32* las_ptr;

__device__ __forceinline__ void gload16(const void* g, void* l) {
  __builtin_amdgcn_global_load_lds((gas_ptr)g, (las_ptr)l, 16, 0, 0);
}

__device__ __forceinline__ ushort_t f2bf(float x) {
  __hip_bfloat16 t = __float2bfloat16(x);
  return *(ushort_t*)&t;
}

__device__ __forceinline__ u32 pk2bf(float x, float y) {
  __hip_bfloat162 t = __float22bfloat162_rn(make_float2(x, y));
  return *(u32*)&t;
}

__device__ __forceinline__ bf16x8 cvt8(f32x4 a, f32x4 b) {
  union { bf16x8 v; u32 u[4]; } r;
  r.u[0] = pk2bf(a.x, a.y); r.u[1] = pk2bf(a.z, a.w);
  r.u[2] = pk2bf(b.x, b.y); r.u[3] = pk2bf(b.z, b.w);
  return r.v;
}

// ---------- setup: X fp32 -> bf16 (same RNE rounding the main loop used) ----------
__global__ void xconv_kernel(const float* __restrict__ X, ushort_t* __restrict__ Xb) {
  int gid = blockIdx.x * 256 + threadIdx.x;   // 0..524287
  #pragma unroll
  for (int i = 0; i < 8; ++i) {
    size_t base = ((size_t)i * 524288 + gid) * 8;
    f32x4 a = *(const f32x4*)(X + base);
    f32x4 b = *(const f32x4*)(X + base + 4);
    *(bf16x8*)(Xb + base) = cvt8(a, b);
  }
}

// ---------- setup: layernorm of slots + fused bq (wave w == head w / 4+w) ----------
__global__ void ln_slots_kernel(const float* __restrict__ slots_w,
                                const float* __restrict__ g, const float* __restrict__ b,
                                const float* __restrict__ bk,
                                float* __restrict__ S, float* __restrict__ bq) {
  __shared__ float red[8];
  int k = blockIdx.x;
  int tid = threadIdx.x;
  float x0 = slots_w[k*D + tid];
  float x1 = slots_w[k*D + tid + 256];
  float s1 = x0 + x1, s2 = x0*x0 + x1*x1;
  for (int off = 32; off; off >>= 1) { s1 += __shfl_xor(s1, off); s2 += __shfl_xor(s2, off); }
  if ((tid & 63) == 0) { red[tid >> 6] = s1; red[4 + (tid >> 6)] = s2; }
  __syncthreads();
  s1 = red[0] + red[1] + red[2] + red[3];
  s2 = red[4] + red[5] + red[6] + red[7];
  float mu = s1 / D;
  float var = s2 / D - mu * mu;
  float rs = rsqrtf(var + LNEPS);
  float y0 = (x0 - mu) * rs * g[tid]       + b[tid];
  float y1 = (x1 - mu) * rs * g[tid + 256] + b[tid + 256];
  S[k*D + tid]       = y0;
  S[k*D + tid + 256] = y1;
  float p0 = y0 * bk[tid];
  float p1 = y1 * bk[tid + 256];
  for (int off = 32; off; off >>= 1) { p0 += __shfl_xor(p0, off); p1 += __shfl_xor(p1, off); }
  if ((tid & 63) == 0) {
    int w = tid >> 6;
    bq[w * KS + k]       = p0 * SCALE;
    bq[(4 + w) * KS + k] = p1 * SCALE;
  }
}

// ---------- fused setup: weff (id<1024) | wvcopy (1024..2047) | zero (2048..) ----------
__global__ void setup_kernel(const float* __restrict__ S, const float* __restrict__ Wk,
                             const float* __restrict__ Wv,
                             ushort_t* __restrict__ Wb2, float* __restrict__ Sacc) {
  int id = blockIdx.x;
  int tid = threadIdx.x;
  if (id < 1024) {
    int gid = id * 256 + tid;
    int in = gid & 511;
    int hk = gid >> 9;
    int h = hk >> 6, k = hk & 63;
    const float* srow = S + k*D + h*HD;
    const float* wcol = Wk + (size_t)(h*HD)*D + in;
    float acc = 0.f;
    #pragma unroll 8
    for (int d = 0; d < HD; ++d) acc += srow[d] * wcol[(size_t)d*D];
    Wb2[(size_t)(h*128 + k)*D + in] = f2bf(acc * SCALE);
  } else if (id < 2048) {
    int gid = (id - 1024) * 256 + tid;
    int in = gid & 511;
    int hd = gid >> 9;
    int h = hd >> 6, d = hd & 63;
    Wb2[(size_t)(h*128 + 64 + d)*D + in] = f2bf(Wv[(size_t)hd*D + in]);
  } else {
    int gid = (id - 2048) * 256 + tid;
    if (gid < 266240) Sacc[gid] = 0.f;
  }
}

// ================= main kernel, bf16-A path (X pre-converted) =================
// Round-2 proven skeleton: 2 LDS buffers per operand, stage(t+1) -> counted
// vmcnt (permutation-invariant "retire all of step t") -> barrier -> compute(t)
// -> barrier. Delta: A is bf16 (8 KB/step, 2 DMA) with a pair-stripe XOR
// swizzle f(p)=(p&~7)|((p&7)^((p>>3)&7)) (involution; applied to global source
// AND read address -> 2-way residual bank conflict). 4 DMA/step -> vmcnt(4).
// LDS 34816 -> 4 blocks/CU.
__global__ __launch_bounds__(256, 4) void main_kernel_b(
    const ushort_t* __restrict__ Xb, const ushort_t* __restrict__ Wb2,
    const float* __restrict__ bq, const float* __restrict__ bv,
    float* __restrict__ Sacc, float* __restrict__ Cacc) {
  __shared__ __align__(16) char smem[34816];
  ushort_t* A0 = (ushort_t*)smem;                     // [512 units of 16B], 8 KB
  ushort_t* A1 = (ushort_t*)(smem + 8192);
  ushort_t* B0 = (ushort_t*)(smem + 16384);           // [128 cols][32 k] bf16, 8 KB
  ushort_t* B1 = (ushort_t*)(smem + 24576);
  ushort_t* W_lds = (ushort_t*)smem;                  // overlay [64][136]
  ushort_t* V_lds = (ushort_t*)(smem + 17408);        // overlay [64][136]

  const int tid  = threadIdx.x;
  const int lane = tid & 63, w = tid >> 6;
  const int wm = w & 1, wn = w >> 1;
  const int m16 = lane & 15, q = lane >> 4;

  const int id = blockIdx.x;
  const int h  = (id >> 3) & 7;
  const int cg = (id & 7) | ((id >> 6) << 3);
  const int bh = (cg >> 5) * H + h;

  const ushort_t* Wp = Wb2 + (size_t)h * 128 * D;

  f32x4 acc2[4] = {};
  float csum[4] = {0.f, 0.f, 0.f, 0.f};

#define STAGE_A(t, AB) do { \
    _Pragma("unroll") \
    for (int m_ = 0; m_ < 2; ++m_) { \
      int p_ = tid + m_ * 256;                         /* phys 16B unit 0..511 */ \
      int g_ = (p_ & ~7) | ((p_ & 7) ^ ((p_ >> 3) & 7)); /* src unit (involution) */ \
      int row_ = g_ >> 2, c_ = g_ & 3; \
      gload16(Xc + (size_t)row_ * D + (t) * 32 + c_ * 8, AB + (size_t)p_ * 8); \
    } \
  } while (0)

#define STAGE_B(t, BB) do { \
    _Pragma("unroll") \
    for (int m_ = 0; m_ < 2; ++m_) { \
      int li_ = tid + m_ * 256; \
      int col_ = li_ >> 2, c_ = li_ & 3; \
      gload16(Wp + (size_t)col_ * D + (t) * 32 + ((c_ ^ ((col_ >> 1) & 3)) * 8), \
              BB + (size_t)li_ * 8); \
    } \
  } while (0)

#define COMPUTE(t, AB, BB) do { \
    bf16x8 af_[4], bf_[4]; \
    _Pragma("unroll") \
    for (int i_ = 0; i_ < 4; ++i_) { \
      int r_ = wm * 64 + i_ * 16 + m16; \
      int g_ = 4 * r_ + q; \
      int p_ = (g_ & ~7) | ((g_ & 7) ^ ((g_ >> 3) & 7)); \
      af_[i_] = *(const bf16x8*)(AB + (size_t)p_ * 8); \
    } \
    _Pragma("unroll") \
    for (int j_ = 0; j_ < 4; ++j_) { \
      int cl_ = wn * 64 + j_ * 16 + m16; \
      bf_[j_] = *(const bf16x8*)(BB + (size_t)cl_ * 32 + ((q ^ ((cl_ >> 1) & 3)) * 8)); \
    } \
    _Pragma("unroll") \
    for (int i_ = 0; i_ < 4; ++i_) \
      _Pragma("unroll") \
      for (int j_ = 0; j_ < 4; ++j_) \
        acc[i_][j_] = __builtin_amdgcn_mfma_f32_16x16x32_bf16(af_[i_], bf_[j_], acc[i_][j_], 0, 0, 0); \
  } while (0)

#define STEP(t, AB, ABN, BB, BBN) do { \
    if ((t) < 15) { \
      STAGE_A((t) + 1, ABN); \
      STAGE_B((t) + 1, BBN); \
      asm volatile("s_waitcnt vmcnt(4)" ::: "memory"); \
    } else { \
      asm volatile("s_waitcnt vmcnt(0)" ::: "memory"); \
    } \
    __builtin_amdgcn_s_barrier(); \
    __builtin_amdgcn_sched_barrier(0); \
    COMPUTE(t, AB, BB); \
    if ((t) < 15) { \
      __builtin_amdgcn_sched_barrier(0); \
      __builtin_amdgcn_s_barrier(); \
    } \
  } while (0)

  for (int cc = 0; cc < CPB; ++cc) {
    const ushort_t* Xc = Xb + (size_t)(cg * CPB + cc) * TC * D;
    f32x4 acc[4][4] = {};

    STAGE_A(0, A0);
    STAGE_B(0, B0);
    __builtin_amdgcn_sched_barrier(0);

    STEP( 0, A0, A1, B0, B1);  STEP( 1, A1, A0, B1, B0);
    STEP( 2, A0, A1, B0, B1);  STEP( 3, A1, A0, B1, B0);
    STEP( 4, A0, A1, B0, B1);  STEP( 5, A1, A0, B1, B0);
    STEP( 6, A0, A1, B0, B1);  STEP( 7, A1, A0, B1, B0);
    STEP( 8, A0, A1, B0, B1);  STEP( 9, A1, A0, B1, B0);
    STEP(10, A0, A1, B0, B1);  STEP(11, A1, A0, B1, B0);
    STEP(12, A0, A1, B0, B1);  STEP(13, A1, A0, B1, B0);
    STEP(14, A0, A1, B0, B1);  STEP(15, A1, A0, B1, B0);

    __syncthreads();   // phase-1 LDS reads done; overlay W/V

    if (wn == 0) {
      float bqv[4];
      #pragma unroll
      for (int j = 0; j < 4; ++j) bqv[j] = bq[h * KS + j * 16 + m16];
      #pragma unroll
      for (int i = 0; i < 4; ++i) {
        us4 wp[4];
        #pragma unroll
        for (int r = 0; r < 4; ++r) {
          float v0 = acc[i][0][r] + bqv[0];
          float v1 = acc[i][1][r] + bqv[1];
          float v2 = acc[i][2][r] + bqv[2];
          float v3 = acc[i][3][r] + bqv[3];
          float mx = fmaxf(fmaxf(v0, v1), fmaxf(v2, v3));
          mx = fmaxf(mx, __shfl_xor(mx, 1));
          mx = fmaxf(mx, __shfl_xor(mx, 2));
          mx = fmaxf(mx, __shfl_xor(mx, 4));
          mx = fmaxf(mx, __shfl_xor(mx, 8));
          v0 = __expf(v0 - mx); v1 = __expf(v1 - mx);
          v2 = __expf(v2 - mx); v3 = __expf(v3 - mx);
          float s = v0 + v1 + v2 + v3;
          s += __shfl_xor(s, 1); s += __shfl_xor(s, 2);
          s += __shfl_xor(s, 4); s += __shfl_xor(s, 8);
          float inv = __builtin_amdgcn_rcpf(s);
          v0 *= inv; v1 *= inv; v2 *= inv; v3 *= inv;
          csum[0] += v0; csum[1] += v1; csum[2] += v2; csum[3] += v3;
          wp[0][r] = f2bf(v0); wp[1][r] = f2bf(v1);
          wp[2][r] = f2bf(v2); wp[3][r] = f2bf(v3);
        }
        #pragma unroll
        for (int j = 0; j < 4; ++j)
          *(us4*)(W_lds + (j * 16 + m16) * 136 + wm * 64 + i * 16 + q * 4) = wp[j];
      }
    } else {
      float bvv[4];
      #pragma unroll
      for (int j = 0; j < 4; ++j) bvv[j] = bv[h * HD + j * 16 + m16];
      #pragma unroll
      for (int i = 0; i < 4; ++i) {
        #pragma unroll
        for (int j = 0; j < 4; ++j) {
          us4 pk;
          pk.x = f2bf(acc[i][j][0] + bvv[j]);
          pk.y = f2bf(acc[i][j][1] + bvv[j]);
          pk.z = f2bf(acc[i][j][2] + bvv[j]);
          pk.w = f2bf(acc[i][j][3] + bvv[j]);
          *(us4*)(V_lds + (j * 16 + m16) * 136 + wm * 64 + i * 16 + q * 4) = pk;
        }
      }
    }
    __syncthreads();

    #pragma unroll
    for (int kk = 0; kk < 4; ++kk) {
      bf16x8 a = *(const bf16x8*)(W_lds + (w * 16 + m16) * 136 + kk * 32 + q * 8);
      #pragma unroll
      for (int j = 0; j < 4; ++j) {
        bf16x8 bb = *(const bf16x8*)(V_lds + (j * 16 + m16) * 136 + kk * 32 + q * 8);
        acc2[j] = __builtin_amdgcn_mfma_f32_16x16x32_bf16(a, bb, acc2[j], 0, 0, 0);
      }
    }
    __syncthreads();
  }

#undef STEP
#undef COMPUTE
#undef STAGE_B
#undef STAGE_A

  float* Sb = Sacc + (size_t)bh * KS * HD;
  #pragma unroll
  for (int j = 0; j < 4; ++j)
    #pragma unroll
    for (int r = 0; r < 4; ++r)
      atomicAdd(Sb + (w * 16 + q * 4 + r) * HD + j * 16 + m16, acc2[j][r]);

  if (wn == 0) {
    #pragma unroll
    for (int j = 0; j < 4; ++j) {
      float c = csum[j];
      c += __shfl_xor(c, 16);
      c += __shfl_xor(c, 32);
      if (q == 0) atomicAdd(Cacc + (size_t)bh * KS + j * 16 + m16, c);
    }
  }
}

// ================= fallback main (fp32 A), exact round-2 kernel =================
__global__ __launch_bounds__(256, 3) void main_kernel_f(
    const float* __restrict__ X, const ushort_t* __restrict__ Wb2,
    const float* __restrict__ bq, const float* __restrict__ bv,
    float* __restrict__ Sacc, float* __restrict__ Cacc) {
  __shared__ __align__(16) char smem[49152];
  float*    A0 = (float*)smem;
  float*    A1 = (float*)(smem + 16384);
  ushort_t* B0 = (ushort_t*)(smem + 32768);
  ushort_t* B1 = (ushort_t*)(smem + 40960);
  ushort_t* W_lds = (ushort_t*)smem;
  ushort_t* V_lds = (ushort_t*)(smem + 17408);

  const int tid  = threadIdx.x;
  const int lane = tid & 63, w = tid >> 6;
  const int wm = w & 1, wn = w >> 1;
  const int m16 = lane & 15, q = lane >> 4;

  const int id = blockIdx.x;
  const int h  = (id >> 3) & 7;
  const int cg = (id & 7) | ((id >> 6) << 3);
  const int bh = (cg >> 5) * H + h;

  const ushort_t* Wp = Wb2 + (size_t)h * 128 * D;

  f32x4 acc2[4] = {};
  float csum[4] = {0.f, 0.f, 0.f, 0.f};

#define F_STAGE(t, AB, BB) do { \
    _Pragma("unroll") \
    for (int m_ = 0; m_ < 4; ++m_) { \
      int li_ = tid + m_ * 256; \
      int row_ = li_ >> 3, c_ = li_ & 7; \
      gload16(Xc + (size_t)row_ * D + (t) * 32 + ((c_ ^ (row_ & 7)) * 4), \
              (AB) + (size_t)li_ * 4); \
    } \
    _Pragma("unroll") \
    for (int m_ = 0; m_ < 2; ++m_) { \
      int li_ = tid + m_ * 256; \
      int col_ = li_ >> 2, c_ = li_ & 3; \
      gload16(Wp + (size_t)col_ * D + (t) * 32 + ((c_ ^ ((col_ >> 1) & 3)) * 8), \
              (BB) + (size_t)li_ * 8); \
    } \
  } while (0)

#define F_COMPUTE(t, AB, BB) do { \
    bf16x8 af_[4], bf_[4]; \
    _Pragma("unroll") \
    for (int i_ = 0; i_ < 4; ++i_) { \
      int r_ = wm * 64 + i_ * 16 + m16; \
      int sw_ = r_ & 7; \
      f32x4 a0_ = *(const f32x4*)((AB) + (size_t)r_ * 32 + (((2 * q)     ^ sw_) * 4)); \
      f32x4 a1_ = *(const f32x4*)((AB) + (size_t)r_ * 32 + (((2 * q + 1) ^ sw_) * 4)); \
      af_[i_] = cvt8(a0_, a1_); \
    } \
    _Pragma("unroll") \
    for (int j_ = 0; j_ < 4; ++j_) { \
      int cl_ = wn * 64 + j_ * 16 + m16; \
      bf_[j_] = *(const bf16x8*)((BB) + (size_t)cl_ * 32 + ((q ^ ((cl_ >> 1) & 3)) * 8)); \
    } \
    _Pragma("unroll") \
    for (int i_ = 0; i_ < 4; ++i_) \
      _Pragma("unroll") \
      for (int j_ = 0; j_ < 4; ++j_) \
        acc[i_][j_] = __builtin_amdgcn_mfma_f32_16x16x32_bf16(af_[i_], bf_[j_], acc[i_][j_], 0, 0, 0); \
  } while (0)

#define F_STEP(t, AB, ABN, BB, BBN) do { \
    if ((t) < 15) { \
      F_STAGE((t) + 1, ABN, BBN); \
      asm volatile("s_waitcnt vmcnt(6)" ::: "memory"); \
    } else { \
      asm volatile("s_waitcnt vmcnt(0)" ::: "memory"); \
    } \
    __builtin_amdgcn_s_barrier(); \
    __builtin_amdgcn_sched_barrier(0); \
    F_COMPUTE(t, AB, BB); \
    if ((t) < 15) { \
      __builtin_amdgcn_sched_barrier(0); \
      __builtin_amdgcn_s_barrier(); \
    } \
  } while (0)

  for (int cc = 0; cc < CPB; ++cc) {
    const float* Xc = X + (size_t)(cg * CPB + cc) * TC * D;
    f32x4 acc[4][4] = {};

    F_STAGE(0, A0, B0);
    __builtin_amdgcn_sched_barrier(0);

    F_STEP( 0, A0, A1, B0, B1);  F_STEP( 1, A1, A0, B1, B0);
    F_STEP( 2, A0, A1, B0, B1);  F_STEP( 3, A1, A0, B1, B0);
    F_STEP( 4, A0, A1, B0, B1);  F_STEP( 5, A1, A0, B1, B0);
    F_STEP( 6, A0, A1, B0, B1);  F_STEP( 7, A1, A0, B1, B0);
    F_STEP( 8, A0, A1, B0, B1);  F_STEP( 9, A1, A0, B1, B0);
    F_STEP(10, A0, A1, B0, B1);  F_STEP(11, A1, A0, B1, B0);
    F_STEP(12, A0, A1, B0, B1);  F_STEP(13, A1, A0, B1, B0);
    F_STEP(14, A0, A1, B0, B1);  F_STEP(15, A1, A0, B1, B0);

    __syncthreads();

    if (wn == 0) {
      float bqv[4];
      #pragma unroll
      for (int j = 0; j < 4; ++j) bqv[j] = bq[h * KS + j * 16 + m16];
      #pragma unroll
      for (int i = 0; i < 4; ++i) {
        us4 wp[4];
        #pragma unroll
        for (int r = 0; r < 4; ++r) {
          float v0 = acc[i][0][r] + bqv[0];
          float v1 = acc[i][1][r] + bqv[1];
          float v2 = acc[i][2][r] + bqv[2];
          float v3 = acc[i][3][r] + bqv[3];
          float mx = fmaxf(fmaxf(v0, v1), fmaxf(v2, v3));
          mx = fmaxf(mx, __shfl_xor(mx, 1));
          mx = fmaxf(mx, __shfl_xor(mx, 2));
          mx = fmaxf(mx, __shfl_xor(mx, 4));
          mx = fmaxf(mx, __shfl_xor(mx, 8));
          v0 = __expf(v0 - mx); v1 = __expf(v1 - mx);
          v2 = __expf(v2 - mx); v3 = __expf(v3 - mx);
          float s = v0 + v1 + v2 + v3;
          s += __shfl_xor(s, 1); s += __shfl_xor(s, 2);
          s += __shfl_xor(s, 4); s += __shfl_xor(s, 8);
          float inv = __builtin_amdgcn_rcpf(s);
          v0 *= inv; v1 *= inv; v2 *= inv; v3 *= inv;
          csum[0] += v0; csum[1] += v1; csum[2] += v2; csum[3] += v3;
          wp[0][r] = f2bf(v0); wp[1][r] = f2bf(v1);
          wp[2][r] = f2bf(v2); wp[3][r] = f2bf(v3);
        }
        #pragma unroll
        for (int j = 0; j < 4; ++j)
          *(us4*)(W_lds + (j * 16 + m16) * 136 + wm * 64 + i * 16 + q * 4) = wp[j];
      }
    } else {
      float bvv[4];
      #pragma unroll
      for (int j = 0; j < 4; ++j) bvv[j] = bv[h * HD + j * 16 + m16];
      #pragma unroll
      for (int i = 0; i < 4; ++i) {
        #pragma unroll
        for (int j = 0; j < 4; ++j) {
          us4 pk;
          pk.x = f2bf(acc[i][j][0] + bvv[j]);
          pk.y = f2bf(acc[i][j][1] + bvv[j]);
          pk.z = f2bf(acc[i][j][2] + bvv[j]);
          pk.w = f2bf(acc[i][j][3] + bvv[j]);
          *(us4*)(V_lds + (j * 16 + m16) * 136 + wm * 64 + i * 16 + q * 4) = pk;
        }
      }
    }
    __syncthreads();

    #pragma unroll
    for (int kk = 0; kk < 4; ++kk) {
      bf16x8 a = *(const bf16x8*)(W_lds + (w * 16 + m16) * 136 + kk * 32 + q * 8);
      #pragma unroll
      for (int j = 0; j < 4; ++j) {
        bf16x8 bb = *(const bf16x8*)(V_lds + (j * 16 + m16) * 136 + kk * 32 + q * 8);
        acc2[j] = __builtin_amdgcn_mfma_f32_16x16x32_bf16(a, bb, acc2[j], 0, 0, 0);
      }
    }
    __syncthreads();
  }

#undef F_STEP
#undef F_COMPUTE
#undef F_STAGE

  float* Sb = Sacc + (size_t)bh * KS * HD;
  #pragma unroll
  for (int j = 0; j < 4; ++j)
    #pragma unroll
    for (int r = 0; r < 4; ++r)
      atomicAdd(Sb + (w * 16 + q * 4 + r) * HD + j * 16 + m16, acc2[j][r]);

  if (wn == 0) {
    #pragma unroll
    for (int j = 0; j < 4; ++j) {
      float c = csum[j];
      c += __shfl_xor(c, 16);
      c += __shfl_xor(c, 32);
      if (q == 0) atomicAdd(Cacc + (size_t)bh * KS + j * 16 + m16, c);
    }
  }
}

// ---------- finalize: divide by (C+eps), layernorm, write out ----------
__global__ void finalize_kernel(const float* __restrict__ Sacc, const float* __restrict__ Cacc,
                                const float* __restrict__ g, const float* __restrict__ bb,
                                float* __restrict__ out) {
  __shared__ float red[8];
  int bk_ = blockIdx.x;
  int b = bk_ >> 6, k = bk_ & 63;
  int tid = threadIdx.x;
  float v[2];
  #pragma unroll
  for (int m = 0; m < 2; ++m) {
    int d = tid + m*256;
    int h = d >> 6, dd = d & 63;
    float c = Cacc[((size_t)b*H + h)*KS + k];
    v[m] = Sacc[(((size_t)b*H + h)*KS + k)*HD + dd] / (c + EPS);
  }
  float s1 = v[0] + v[1], s2 = v[0]*v[0] + v[1]*v[1];
  for (int off = 32; off; off >>= 1) { s1 += __shfl_xor(s1, off); s2 += __shfl_xor(s2, off); }
  if ((tid & 63) == 0) { red[tid >> 6] = s1; red[4 + (tid >> 6)] = s2; }
  __syncthreads();
  s1 = red[0] + red[1] + red[2] + red[3];
  s2 = red[4] + red[5] + red[6] + red[7];
  float mu = s1 / D;
  float var = s2 / D - mu * mu;
  float rs = rsqrtf(var + LNEPS);
  #pragma unroll
  for (int m = 0; m < 2; ++m) {
    int d = tid + m*256;
    out[(size_t)bk_*D + d] = (v[m] - mu) * rs * g[d] + bb[d];
  }
}

extern "C" void kernel_launch(void* const* d_in, const int* in_sizes, int n_in,
                              void* d_out, int out_size, void* d_ws, size_t ws_size,
                              hipStream_t stream) {
  const float* X       = (const float*)d_in[0];
  const float* slots_w = (const float*)d_in[1];
  const float* g_slots = (const float*)d_in[2];
  const float* b_slots = (const float*)d_in[3];
  const float* Wk      = (const float*)d_in[4];
  const float* bk      = (const float*)d_in[5];
  const float* Wv      = (const float*)d_in[6];
  const float* bv      = (const float*)d_in[7];
  const float* g_after = (const float*)d_in[8];
  const float* b_after = (const float*)d_in[9];
  float* ws   = (float*)d_ws;
  float* S    = ws + OFF_S;
  float* bq   = ws + OFF_BQ;
  float* Sacc = ws + OFF_SACC;
  float* Cacc = ws + OFF_CACC;
  ushort_t* Wb2 = (ushort_t*)(ws + OFF_WB2);
  ushort_t* Xb  = (ushort_t*)(ws + OFF_XB);
  float* out  = (float*)d_out;

  const size_t need_bytes = OFF_XB * 4 + (size_t)B * T * D * 2;  // 66.2 MB
  const bool big_ws = ws_size >= need_bytes;

  hipLaunchKernelGGL(ln_slots_kernel, dim3(64), dim3(256), 0, stream,
                     slots_w, g_slots, b_slots, bk, S, bq);
  hipLaunchKernelGGL(setup_kernel, dim3(3088), dim3(256), 0, stream, S, Wk, Wv, Wb2, Sacc);
  if (big_ws) {
    hipLaunchKernelGGL(xconv_kernel, dim3(2048), dim3(256), 0, stream, X, Xb);
    hipLaunchKernelGGL(main_kernel_b, dim3(2048), dim3(256), 0, stream, Xb, Wb2, bq, bv, Sacc, Cacc);
  } else {
    hipLaunchKernelGGL(main_kernel_f, dim3(2048), dim3(256), 0, stream, X, Wb2, bq, bv, Sacc, Cacc);
  }
  hipLaunchKernelGGL(finalize_kernel, dim3(B * KS), dim3(256), 0, stream,
                     Sacc, Cacc, g_after, b_after, out);
}

// Round 8
// 404.865 us; speedup vs baseline: 1.9399x; 1.0302x over previous
//
#include <hip/hip_runtime.h>
#include <hip/hip_bf16.h>
#include <math.h>

typedef unsigned short ushort_t;
typedef unsigned int u32;

constexpr int D  = 512;
constexpr int T  = 8192;
constexpr int B  = 8;
constexpr int H  = 8;
constexpr int KS = 64;
constexpr int HD = 64;
constexpr float SCALE = 0.125f;
constexpr float LNEPS = 1e-5f;
constexpr float EPS   = 1e-20f;

constexpr int TC  = 128;   // tokens per chunk
constexpr int CPB = 2;     // chunks per block

// ws layout (float units)
constexpr size_t OFF_S    = 0;         // 64*512
constexpr size_t OFF_BQ   = 32768;     // 512
constexpr size_t OFF_SACC = 33280;     // 8*8*64*64 = 262144
constexpr size_t OFF_CACC = 295424;    // 8*8*64 = 4096
constexpr size_t OFF_WB2  = 299520;    // bf16[1024*512] (1 MB)

typedef __attribute__((ext_vector_type(8))) short bf16x8;
typedef __attribute__((ext_vector_type(4))) float f32x4;
typedef __attribute__((ext_vector_type(4))) unsigned short us4;

typedef const __attribute__((address_space(1))) u32* gas_ptr;
typedef __attribute__((address_space(3))) u32* las_ptr;

__device__ __forceinline__ void gload16(const void* g, void* l) {
  __builtin_amdgcn_global_load_lds((gas_ptr)g, (las_ptr)l, 16, 0, 0);
}

__device__ __forceinline__ ushort_t f2bf(float x) {
  __hip_bfloat16 t = __float2bfloat16(x);
  return *(ushort_t*)&t;
}

__device__ __forceinline__ u32 pk2bf(float x, float y) {
  __hip_bfloat162 t = __float22bfloat162_rn(make_float2(x, y));
  return *(u32*)&t;
}

__device__ __forceinline__ bf16x8 cvt8(f32x4 a, f32x4 b) {
  union { bf16x8 v; u32 u[4]; } r;
  r.u[0] = pk2bf(a.x, a.y); r.u[1] = pk2bf(a.z, a.w);
  r.u[2] = pk2bf(b.x, b.y); r.u[3] = pk2bf(b.z, b.w);
  return r.v;
}

// ---------- setup: layernorm of slots + fused bq (wave w == head w / 4+w) ----------
__global__ void ln_slots_kernel(const float* __restrict__ slots_w,
                                const float* __restrict__ g, const float* __restrict__ b,
                                const float* __restrict__ bk,
                                float* __restrict__ S, float* __restrict__ bq) {
  __shared__ float red[8];
  int k = blockIdx.x;
  int tid = threadIdx.x;
  float x0 = slots_w[k*D + tid];
  float x1 = slots_w[k*D + tid + 256];
  float s1 = x0 + x1, s2 = x0*x0 + x1*x1;
  for (int off = 32; off; off >>= 1) { s1 += __shfl_xor(s1, off); s2 += __shfl_xor(s2, off); }
  if ((tid & 63) == 0) { red[tid >> 6] = s1; red[4 + (tid >> 6)] = s2; }
  __syncthreads();
  s1 = red[0] + red[1] + red[2] + red[3];
  s2 = red[4] + red[5] + red[6] + red[7];
  float mu = s1 / D;
  float var = s2 / D - mu * mu;
  float rs = rsqrtf(var + LNEPS);
  float y0 = (x0 - mu) * rs * g[tid]       + b[tid];
  float y1 = (x1 - mu) * rs * g[tid + 256] + b[tid + 256];
  S[k*D + tid]       = y0;
  S[k*D + tid + 256] = y1;
  float p0 = y0 * bk[tid];
  float p1 = y1 * bk[tid + 256];
  for (int off = 32; off; off >>= 1) { p0 += __shfl_xor(p0, off); p1 += __shfl_xor(p1, off); }
  if ((tid & 63) == 0) {
    int w = tid >> 6;
    bq[w * KS + k]       = p0 * SCALE;
    bq[(4 + w) * KS + k] = p1 * SCALE;
  }
}

// ---------- fused setup: weff (id<1024) | wvcopy (1024..2047) | zero (2048..) ----------
__global__ void setup_kernel(const float* __restrict__ S, const float* __restrict__ Wk,
                             const float* __restrict__ Wv,
                             ushort_t* __restrict__ Wb2, float* __restrict__ Sacc) {
  int id = blockIdx.x;
  int tid = threadIdx.x;
  if (id < 1024) {
    int gid = id * 256 + tid;
    int in = gid & 511;
    int hk = gid >> 9;
    int h = hk >> 6, k = hk & 63;
    const float* srow = S + k*D + h*HD;
    const float* wcol = Wk + (size_t)(h*HD)*D + in;
    float acc = 0.f;
    #pragma unroll 8
    for (int d = 0; d < HD; ++d) acc += srow[d] * wcol[(size_t)d*D];
    Wb2[(size_t)(h*128 + k)*D + in] = f2bf(acc * SCALE);
  } else if (id < 2048) {
    int gid = (id - 1024) * 256 + tid;
    int in = gid & 511;
    int hd = gid >> 9;
    int h = hd >> 6, d = hd & 63;
    Wb2[(size_t)(h*128 + 64 + d)*D + in] = f2bf(Wv[(size_t)hd*D + in]);
  } else {
    int gid = (id - 2048) * 256 + tid;
    if (gid < 266240) Sacc[gid] = 0.f;
  }
}

// ---------- main fused MFMA kernel ----------
// grid = 2048 blocks, 256 threads (4 waves, 2x2 wave grid).
// SINGLE-BARRIER K-step (T14 async-split staging):
//   top:   GLOAD A(t+2) fp32 -> regs (4 plain loads), sealed as newest
//          vmcnt(4) = retire all but those 4  [permutation-invariant]
//          lgkmcnt(0) (drain my prev ds_writes) ; s_barrier ; seal
//   body:  STAGE_B(t+1) via global_load_lds (issue overlaps MFMA; its target
//          buffer's readers finished before this barrier -> 2 buffers safe)
//          COMPUTE(t) from LDS (bf16 A + bf16 B, both XOR-swizzled 2-way)
//          CVT(A(t+1) regs -> bf16) + ds_write into A[(t+1)&1] (readers of that
//          buffer were step t-1, done before this barrier) ; seal
// A in LDS is bf16 (8 KB/buf): halves A LDS traffic vs round 2 and removes
// the in-COMPUTE cvt. No xconv kernel (X stays fp32 in HBM, read once).
__global__ __launch_bounds__(256, 3) void main_kernel(
    const float* __restrict__ X, const ushort_t* __restrict__ Wb2,
    const float* __restrict__ bq, const float* __restrict__ bv,
    float* __restrict__ Sacc, float* __restrict__ Cacc) {
  __shared__ __align__(16) char smem[34816];
  ushort_t* A_lds0 = (ushort_t*)smem;                 // [128][32] bf16, 8 KB
  ushort_t* A_lds1 = (ushort_t*)(smem + 8192);
  ushort_t* B_lds0 = (ushort_t*)(smem + 16384);       // [128 cols][32 k] bf16, 8 KB
  ushort_t* B_lds1 = (ushort_t*)(smem + 24576);
  ushort_t* W_lds  = (ushort_t*)smem;                 // overlay [64][136]
  ushort_t* V_lds  = (ushort_t*)(smem + 17408);       // overlay [64][136]

  const int tid  = threadIdx.x;
  const int lane = tid & 63, w = tid >> 6;
  const int wm = w & 1, wn = w >> 1;
  const int m16 = lane & 15, q = lane >> 4;

  const int id = blockIdx.x;
  const int h  = (id >> 3) & 7;
  const int cg = (id & 7) | ((id >> 6) << 3);
  const int bh = (cg >> 5) * H + h;

  const ushort_t* Wp = Wb2 + (size_t)h * 128 * D;

  f32x4 acc2[4] = {};
  float csum[4] = {0.f, 0.f, 0.f, 0.f};

// A: thread covers row r = tid>>1, k-half hf = tid&1 (16 fp32, 64B contiguous)
#define GLOAD_A(t, S0, S1, S2, S3) do { \
    const float* gp_ = Xc + (size_t)(tid >> 1) * D + (t) * 32 + (tid & 1) * 16; \
    S0 = *(const f32x4*)(gp_);      S1 = *(const f32x4*)(gp_ + 4); \
    S2 = *(const f32x4*)(gp_ + 8);  S3 = *(const f32x4*)(gp_ + 12); \
  } while (0)

// cvt 16 fp32 -> 16 bf16, write 2x16B with unit-swizzle u' = u ^ ((r>>1)&3)
#define CVT_WRITE(S0, S1, S2, S3, AB) do { \
    int r_ = tid >> 1, hf_ = tid & 1; \
    int sw_ = (r_ >> 1) & 3; \
    bf16x8 lo_ = cvt8(S0, S1); \
    bf16x8 hi_ = cvt8(S2, S3); \
    *(bf16x8*)((AB) + r_ * 32 + (((2 * hf_)     ^ sw_) * 8)) = lo_; \
    *(bf16x8*)((AB) + r_ * 32 + (((2 * hf_ + 1) ^ sw_) * 8)) = hi_; \
  } while (0)

#define STAGE_B(t, BB) do { \
    _Pragma("unroll") \
    for (int m_ = 0; m_ < 2; ++m_) { \
      int li_ = tid + m_ * 256; \
      int col_ = li_ >> 2, c_ = li_ & 3; \
      gload16(Wp + (size_t)col_ * D + (t) * 32 + ((c_ ^ ((col_ >> 1) & 3)) * 8), \
              (BB) + (size_t)li_ * 8); \
    } \
  } while (0)

#define COMPUTE(t, AB, BB) do { \
    bf16x8 af_[4], bf_[4]; \
    _Pragma("unroll") \
    for (int i_ = 0; i_ < 4; ++i_) { \
      int r_ = wm * 64 + i_ * 16 + m16; \
      int sw_ = (r_ >> 1) & 3; \
      af_[i_] = *(const bf16x8*)((AB) + r_ * 32 + ((q ^ sw_) * 8)); \
    } \
    _Pragma("unroll") \
    for (int j_ = 0; j_ < 4; ++j_) { \
      int cl_ = wn * 64 + j_ * 16 + m16; \
      bf_[j_] = *(const bf16x8*)((BB) + (size_t)cl_ * 32 + ((q ^ ((cl_ >> 1) & 3)) * 8)); \
    } \
    _Pragma("unroll") \
    for (int i_ = 0; i_ < 4; ++i_) \
      _Pragma("unroll") \
      for (int j_ = 0; j_ < 4; ++j_) \
        acc[i_][j_] = __builtin_amdgcn_mfma_f32_16x16x32_bf16(af_[i_], bf_[j_], acc[i_][j_], 0, 0, 0); \
  } while (0)

// one K-step; WAITN: t<=13 -> "4", t=14/15 -> "0"
#define STEP(t, WAITN, AB, ABN, BB, BBN, C0,C1,C2,C3, N0,N1,N2,N3) do { \
    if ((t) + 2 < 16) { GLOAD_A((t) + 2, N0, N1, N2, N3); } \
    __builtin_amdgcn_sched_barrier(0); \
    asm volatile("s_waitcnt vmcnt(" WAITN ")" ::: "memory"); \
    asm volatile("s_waitcnt lgkmcnt(0)" ::: "memory"); \
    __builtin_amdgcn_s_barrier(); \
    __builtin_amdgcn_sched_barrier(0); \
    if ((t) + 1 < 16) { STAGE_B((t) + 1, BBN); } \
    COMPUTE(t, AB, BB); \
    if ((t) + 1 < 16) { CVT_WRITE(C0, C1, C2, C3, ABN); } \
    __builtin_amdgcn_sched_barrier(0); \
  } while (0)

  for (int cc = 0; cc < CPB; ++cc) {
    const float* Xc = X + (size_t)(cg * CPB + cc) * TC * D;
    f32x4 acc[4][4] = {};
    // two register sets for in-flight A steps (static names, no dynamic idx)
    f32x4 sa0, sa1, sa2, sa3;   // set0
    f32x4 sb0, sb1, sb2, sb3;   // set1

    // prologue: A(0)->set0 [sealed oldest]; B(0) DMA + A(1)->set1 [sealed];
    // vmcnt(6) retires set0 (oldest 4), keeps {B0, A1}=6; cvt+write A(0)->A_lds0
    GLOAD_A(0, sa0, sa1, sa2, sa3);
    __builtin_amdgcn_sched_barrier(0);
    STAGE_B(0, B_lds0);
    GLOAD_A(1, sb0, sb1, sb2, sb3);
    __builtin_amdgcn_sched_barrier(0);
    asm volatile("s_waitcnt vmcnt(6)" ::: "memory");
    CVT_WRITE(sa0, sa1, sa2, sa3, A_lds0);
    __builtin_amdgcn_sched_barrier(0);

    // even t: compute A_lds0/B_lds0, cvt set1->A_lds1, gload into set0
    // odd  t: compute A_lds1/B_lds1, cvt set0->A_lds0, gload into set1
    STEP( 0, "4", A_lds0, A_lds1, B_lds0, B_lds1, sb0,sb1,sb2,sb3, sa0,sa1,sa2,sa3);
    STEP( 1, "4", A_lds1, A_lds0, B_lds1, B_lds0, sa0,sa1,sa2,sa3, sb0,sb1,sb2,sb3);
    STEP( 2, "4", A_lds0, A_lds1, B_lds0, B_lds1, sb0,sb1,sb2,sb3, sa0,sa1,sa2,sa3);
    STEP( 3, "4", A_lds1, A_lds0, B_lds1, B_lds0, sa0,sa1,sa2,sa3, sb0,sb1,sb2,sb3);
    STEP( 4, "4", A_lds0, A_lds1, B_lds0, B_lds1, sb0,sb1,sb2,sb3, sa0,sa1,sa2,sa3);
    STEP( 5, "4", A_lds1, A_lds0, B_lds1, B_lds0, sa0,sa1,sa2,sa3, sb0,sb1,sb2,sb3);
    STEP( 6, "4", A_lds0, A_lds1, B_lds0, B_lds1, sb0,sb1,sb2,sb3, sa0,sa1,sa2,sa3);
    STEP( 7, "4", A_lds1, A_lds0, B_lds1, B_lds0, sa0,sa1,sa2,sa3, sb0,sb1,sb2,sb3);
    STEP( 8, "4", A_lds0, A_lds1, B_lds0, B_lds1, sb0,sb1,sb2,sb3, sa0,sa1,sa2,sa3);
    STEP( 9, "4", A_lds1, A_lds0, B_lds1, B_lds0, sa0,sa1,sa2,sa3, sb0,sb1,sb2,sb3);
    STEP(10, "4", A_lds0, A_lds1, B_lds0, B_lds1, sb0,sb1,sb2,sb3, sa0,sa1,sa2,sa3);
    STEP(11, "4", A_lds1, A_lds0, B_lds1, B_lds0, sa0,sa1,sa2,sa3, sb0,sb1,sb2,sb3);
    STEP(12, "4", A_lds0, A_lds1, B_lds0, B_lds1, sb0,sb1,sb2,sb3, sa0,sa1,sa2,sa3);
    STEP(13, "4", A_lds1, A_lds0, B_lds1, B_lds0, sa0,sa1,sa2,sa3, sb0,sb1,sb2,sb3);
    STEP(14, "0", A_lds0, A_lds1, B_lds0, B_lds1, sb0,sb1,sb2,sb3, sa0,sa1,sa2,sa3);
    STEP(15, "0", A_lds1, A_lds0, B_lds1, B_lds0, sa0,sa1,sa2,sa3, sb0,sb1,sb2,sb3);

    __syncthreads();   // phase-1 LDS reads done; overlay W/V

    if (wn == 0) {
      float bqv[4];
      #pragma unroll
      for (int j = 0; j < 4; ++j) bqv[j] = bq[h * KS + j * 16 + m16];
      #pragma unroll
      for (int i = 0; i < 4; ++i) {
        us4 wp[4];
        #pragma unroll
        for (int r = 0; r < 4; ++r) {
          float v0 = acc[i][0][r] + bqv[0];
          float v1 = acc[i][1][r] + bqv[1];
          float v2 = acc[i][2][r] + bqv[2];
          float v3 = acc[i][3][r] + bqv[3];
          float mx = fmaxf(fmaxf(v0, v1), fmaxf(v2, v3));
          mx = fmaxf(mx, __shfl_xor(mx, 1));
          mx = fmaxf(mx, __shfl_xor(mx, 2));
          mx = fmaxf(mx, __shfl_xor(mx, 4));
          mx = fmaxf(mx, __shfl_xor(mx, 8));
          v0 = __expf(v0 - mx); v1 = __expf(v1 - mx);
          v2 = __expf(v2 - mx); v3 = __expf(v3 - mx);
          float s = v0 + v1 + v2 + v3;
          s += __shfl_xor(s, 1); s += __shfl_xor(s, 2);
          s += __shfl_xor(s, 4); s += __shfl_xor(s, 8);
          float inv = __builtin_amdgcn_rcpf(s);
          v0 *= inv; v1 *= inv; v2 *= inv; v3 *= inv;
          csum[0] += v0; csum[1] += v1; csum[2] += v2; csum[3] += v3;
          wp[0][r] = f2bf(v0); wp[1][r] = f2bf(v1);
          wp[2][r] = f2bf(v2); wp[3][r] = f2bf(v3);
        }
        #pragma unroll
        for (int j = 0; j < 4; ++j)
          *(us4*)(W_lds + (j * 16 + m16) * 136 + wm * 64 + i * 16 + q * 4) = wp[j];
      }
    } else {
      float bvv[4];
      #pragma unroll
      for (int j = 0; j < 4; ++j) bvv[j] = bv[h * HD + j * 16 + m16];
      #pragma unroll
      for (int i = 0; i < 4; ++i) {
        #pragma unroll
        for (int j = 0; j < 4; ++j) {
          us4 pk;
          pk.x = f2bf(acc[i][j][0] + bvv[j]);
          pk.y = f2bf(acc[i][j][1] + bvv[j]);
          pk.z = f2bf(acc[i][j][2] + bvv[j]);
          pk.w = f2bf(acc[i][j][3] + bvv[j]);
          *(us4*)(V_lds + (j * 16 + m16) * 136 + wm * 64 + i * 16 + q * 4) = pk;
        }
      }
    }
    __syncthreads();

    #pragma unroll
    for (int kk = 0; kk < 4; ++kk) {
      bf16x8 a = *(const bf16x8*)(W_lds + (w * 16 + m16) * 136 + kk * 32 + q * 8);
      #pragma unroll
      for (int j = 0; j < 4; ++j) {
        bf16x8 bb = *(const bf16x8*)(V_lds + (j * 16 + m16) * 136 + kk * 32 + q * 8);
        acc2[j] = __builtin_amdgcn_mfma_f32_16x16x32_bf16(a, bb, acc2[j], 0, 0, 0);
      }
    }
    __syncthreads();   // phase-2 reads done before next chunk's staging
  }

#undef STEP
#undef COMPUTE
#undef STAGE_B
#undef CVT_WRITE
#undef GLOAD_A

  float* Sb = Sacc + (size_t)bh * KS * HD;
  #pragma unroll
  for (int j = 0; j < 4; ++j)
    #pragma unroll
    for (int r = 0; r < 4; ++r)
      atomicAdd(Sb + (w * 16 + q * 4 + r) * HD + j * 16 + m16, acc2[j][r]);

  if (wn == 0) {
    #pragma unroll
    for (int j = 0; j < 4; ++j) {
      float c = csum[j];
      c += __shfl_xor(c, 16);
      c += __shfl_xor(c, 32);
      if (q == 0) atomicAdd(Cacc + (size_t)bh * KS + j * 16 + m16, c);
    }
  }
}

// ---------- finalize: divide by (C+eps), layernorm, write out ----------
__global__ void finalize_kernel(const float* __restrict__ Sacc, const float* __restrict__ Cacc,
                                const float* __restrict__ g, const float* __restrict__ bb,
                                float* __restrict__ out) {
  __shared__ float red[8];
  int bk_ = blockIdx.x;
  int b = bk_ >> 6, k = bk_ & 63;
  int tid = threadIdx.x;
  float v[2];
  #pragma unroll
  for (int m = 0; m < 2; ++m) {
    int d = tid + m*256;
    int h = d >> 6, dd = d & 63;
    float c = Cacc[((size_t)b*H + h)*KS + k];
    v[m] = Sacc[(((size_t)b*H + h)*KS + k)*HD + dd] / (c + EPS);
  }
  float s1 = v[0] + v[1], s2 = v[0]*v[0] + v[1]*v[1];
  for (int off = 32; off; off >>= 1) { s1 += __shfl_xor(s1, off); s2 += __shfl_xor(s2, off); }
  if ((tid & 63) == 0) { red[tid >> 6] = s1; red[4 + (tid >> 6)] = s2; }
  __syncthreads();
  s1 = red[0] + red[1] + red[2] + red[3];
  s2 = red[4] + red[5] + red[6] + red[7];
  float mu = s1 / D;
  float var = s2 / D - mu * mu;
  float rs = rsqrtf(var + LNEPS);
  #pragma unroll
  for (int m = 0; m < 2; ++m) {
    int d = tid + m*256;
    out[(size_t)bk_*D + d] = (v[m] - mu) * rs * g[d] + bb[d];
  }
}

extern "C" void kernel_launch(void* const* d_in, const int* in_sizes, int n_in,
                              void* d_out, int out_size, void* d_ws, size_t ws_size,
                              hipStream_t stream) {
  const float* X       = (const float*)d_in[0];
  const float* slots_w = (const float*)d_in[1];
  const float* g_slots = (const float*)d_in[2];
  const float* b_slots = (const float*)d_in[3];
  const float* Wk      = (const float*)d_in[4];
  const float* bk      = (const float*)d_in[5];
  const float* Wv      = (const float*)d_in[6];
  const float* bv      = (const float*)d_in[7];
  const float* g_after = (const float*)d_in[8];
  const float* b_after = (const float*)d_in[9];
  float* ws   = (float*)d_ws;
  float* S    = ws + OFF_S;
  float* bq   = ws + OFF_BQ;
  float* Sacc = ws + OFF_SACC;
  float* Cacc = ws + OFF_CACC;
  ushort_t* Wb2 = (ushort_t*)(ws + OFF_WB2);
  float* out  = (float*)d_out;

  hipLaunchKernelGGL(ln_slots_kernel, dim3(64), dim3(256), 0, stream,
                     slots_w, g_slots, b_slots, bk, S, bq);
  hipLaunchKernelGGL(setup_kernel, dim3(3088), dim3(256), 0, stream, S, Wk, Wv, Wb2, Sacc);
  hipLaunchKernelGGL(main_kernel, dim3(2048), dim3(256), 0, stream, X, Wb2, bq, bv, Sacc, Cacc);
  hipLaunchKernelGGL(finalize_kernel, dim3(B * KS), dim3(256), 0, stream,
                     Sacc, Cacc, g_after, b_after, out);
}